// Round 1
// 60.150 us; speedup vs baseline: 1.0298x; 1.0298x over previous
//
#include <hip/hip_runtime.h>

// Problem constants (from reference)
#define BATCH 64
#define LEXPR 8192
#define FSUB  100
#define VOCAB 64
#define TPB   512
#define NS    8                 // slices per batch row
#define SLICE (LEXPR / NS)      // 1024 positions owned per block
#define TAIL  (FSUB - 1)        // 99 overlap elements needed past the slice

// R5 structure: 512 blocks (8 slices x 64 rows) so all 256 CUs are busy
// (R3's 64-block layout left 75% of the chip idle; measured residual after
// the harness's 40us workspace-poison fill was ~21.5us of kernel).
// Each block owns positions p in [k*1024, (k+1)*1024). score[p] needs only
// expr[p .. p+99], so the block loads 1024+99 expr elements and computes its
// positions COMPLETELY — no cross-block partial sums. Per-block best packed
// key -> ws[blk] (plain store, poison-safe: every slot written before read),
// tiny finalize kernel maxes the 8 keys per row.
// Packed key (score<<14)|(16383-p): max key == max score, ties -> smallest p
// (first-occurrence argmax, matching jnp.argmax). Position 8192 elided:
// score==0 there and its key 8191 < key(p=0)=16383, so it can never win.
// mask rows padded to stride 5: bank (5v+k)&31 is bijective mod 32 -> <=2-way
// (free) instead of the old stride-4 8-way conflict on mask reads.
__global__ __launch_bounds__(TPB)
void Finder_66640712565346_scatter(const int* __restrict__ expr,
                                   const int* __restrict__ sub,
                                   unsigned int* __restrict__ wskey) {
    __shared__ unsigned int mask[VOCAB][5];            // 100-bit sub-pos masks, padded
    __shared__ __align__(16) unsigned int score[SLICE]; // 4 KB
    __shared__ unsigned int wred[TPB / 64];

    const int blk  = blockIdx.x;
    const int b    = blk >> 3;          // batch row
    const int k    = blk & (NS - 1);    // slice index
    const int base = k * SLICE;
    const int tid  = threadIdx.x;

    // Issue all global loads up front — latency hides behind LDS zeroing.
    const int2* erow2 = (const int2*)(expr + b * LEXPR + base);
    int2 e = erow2[tid];                               // jl = 2*tid, 2*tid+1
    int tv = 0;
    if (tid < TAIL) {                                  // overlap tail jl = SLICE+tid
        int j = base + SLICE + tid;
        tv = (j < LEXPR) ? expr[b * LEXPR + j] : 0;    // j>=L: v=0, mask[0]==0 (PAD filtered)
    }
    int sv = (tid < FSUB) ? sub[b * FSUB + tid] : 0;

    // Zero score (256 uint4) and mask (320 words).
    if (tid < SLICE / 4) ((uint4*)score)[tid] = make_uint4(0u, 0u, 0u, 0u);
    if (tid < VOCAB * 5) ((unsigned int*)mask)[tid] = 0u;
    __syncthreads();

    // Per-vocab bitmask of sub positions; PAD (0) contributes nothing.
    if (sv != 0) atomicOr(&mask[sv][tid >> 5], 1u << (tid & 31));
    __syncthreads();

    // Scatter: main 1024 elements (2 per thread). pl = jl - f <= jl < SLICE,
    // so only the lower bound needs checking.
    #pragma unroll
    for (int e2 = 0; e2 < 2; ++e2) {
        int v  = (e2 == 0) ? e.x : e.y;
        int jl = tid * 2 + e2;
        unsigned int m0 = mask[v][0];
        unsigned int m1 = mask[v][1];
        unsigned int m2 = mask[v][2];
        unsigned int m3 = mask[v][3];
        while (m0) { int f =      __builtin_ctz(m0); m0 &= m0 - 1u; int pl = jl - f; if (pl >= 0) atomicAdd(&score[pl], 1u); }
        while (m1) { int f = 32 + __builtin_ctz(m1); m1 &= m1 - 1u; int pl = jl - f; if (pl >= 0) atomicAdd(&score[pl], 1u); }
        while (m2) { int f = 64 + __builtin_ctz(m2); m2 &= m2 - 1u; int pl = jl - f; if (pl >= 0) atomicAdd(&score[pl], 1u); }
        while (m3) { int f = 96 + __builtin_ctz(m3); m3 &= m3 - 1u; int pl = jl - f; if (pl >= 0) atomicAdd(&score[pl], 1u); }
    }
    // Overlap tail: jl in [SLICE, SLICE+98]; pl >= SLICE-99 >= 0 always,
    // only the upper bound needs checking.
    if (tid < TAIL) {
        int jl = SLICE + tid;
        int v  = tv;
        unsigned int m0 = mask[v][0];
        unsigned int m1 = mask[v][1];
        unsigned int m2 = mask[v][2];
        unsigned int m3 = mask[v][3];
        while (m0) { int f =      __builtin_ctz(m0); m0 &= m0 - 1u; int pl = jl - f; if (pl < SLICE) atomicAdd(&score[pl], 1u); }
        while (m1) { int f = 32 + __builtin_ctz(m1); m1 &= m1 - 1u; int pl = jl - f; if (pl < SLICE) atomicAdd(&score[pl], 1u); }
        while (m2) { int f = 64 + __builtin_ctz(m2); m2 &= m2 - 1u; int pl = jl - f; if (pl < SLICE) atomicAdd(&score[pl], 1u); }
        while (m3) { int f = 96 + __builtin_ctz(m3); m3 &= m3 - 1u; int pl = jl - f; if (pl < SLICE) atomicAdd(&score[pl], 1u); }
    }
    __syncthreads();

    // Packed-key max over the owned slice (uint2 per thread).
    unsigned int best = 0u;
    {
        uint2 v = ((const uint2*)score)[tid];
        unsigned int pb = 16383u - (unsigned int)(base + tid * 2);
        unsigned int kk;
        kk = (v.x << 14) | pb;        if (kk > best) best = kk;
        kk = (v.y << 14) | (pb - 1u); if (kk > best) best = kk;
    }
    #pragma unroll
    for (int off = 32; off > 0; off >>= 1) {
        unsigned int o = __shfl_down(best, off, 64);
        if (o > best) best = o;
    }
    if ((tid & 63) == 0) wred[tid >> 6] = best;
    __syncthreads();
    if (tid == 0) {
        unsigned int m = wred[0];
        #pragma unroll
        for (int w = 1; w < TPB / 64; ++w) if (wred[w] > m) m = wred[w];
        wskey[blk] = m;   // plain store; finalize kernel reads after dispatch boundary
    }
}

__global__ __launch_bounds__(BATCH)
void Finder_66640712565346_finalize(const unsigned int* __restrict__ wskey,
                                    float* __restrict__ out) {
    int b = threadIdx.x;
    unsigned int m = wskey[b * NS];
    #pragma unroll
    for (int i = 1; i < NS; ++i) {
        unsigned int v = wskey[b * NS + i];
        if (v > m) m = v;
    }
    out[b]         = (float)(16383u - (m & 16383u));  // position
    out[BATCH + b] = (float)(m >> 14);                // max score
}

extern "C" void kernel_launch(void* const* d_in, const int* in_sizes, int n_in,
                              void* d_out, int out_size, void* d_ws, size_t ws_size,
                              hipStream_t stream) {
    const int* expr = (const int*)d_in[0];  // [64, 8192] int32
    const int* sub  = (const int*)d_in[1];  // [64, 100] int32
    float* out = (float*)d_out;             // [64] positions ++ [64] max scores
    unsigned int* wskey = (unsigned int*)d_ws;  // 512 packed keys (poison-safe)

    Finder_66640712565346_scatter<<<BATCH * NS, TPB, 0, stream>>>(expr, sub, wskey);
    Finder_66640712565346_finalize<<<1, BATCH, 0, stream>>>(wskey, out);
}